// Round 5
// baseline (270.232 us; speedup 1.0000x reference)
//
#include <hip/hip_runtime.h>
#include <hip/hip_bf16.h>
#include <stdint.h>

#define NE    64
#define DIN   512
#define DOUT  512
#define TTOK  131072
#define BM    256
#define BN    128
#define BK    32
#define NK    (DIN / BK)              // 16 K-steps
#define TILES_TOTAL (TTOK / BM + NE)  // 576: sum ceil(c_e/BM) <= T/BM + E
#define NXCD  8
#define TPX   (TILES_TOTAL / NXCD)    // 72

typedef __bf16 bf16x8_t __attribute__((ext_vector_type(8)));
typedef __bf16 bf16x4_t __attribute__((ext_vector_type(4)));
typedef float  f32x4_t  __attribute__((ext_vector_type(4)));

// LDS map (bytes):
//   A ring: 3 x 32768 at 0/32768/65536   (256 rows x 128B fp32; source-preswizzled)
//   B dbuf: 2 x 8192  at 98304/106496    (128 rows x 64B bf16; XOR swizzled)
#define LDS_BYTES 114688
#define ABUF(i) ((i) * 32768)
#define BBUF(i) (98304 + (i) * 8192)

// ws layout: ws[0] = ntiles; tile table at ws+4 (int4: e, row0, row_end, pad)
__global__ void setup_tiles(const int* __restrict__ cnt, int* __restrict__ ws) {
    int e = threadIdx.x;
    if (e >= NE) return;
    int off = 0, tbase = 0;
    for (int i = 0; i < e; ++i) {
        int c = cnt[i];
        off += c;
        tbase += (c + (BM - 1)) / BM;
    }
    int c = cnt[e];
    int nt = (c + (BM - 1)) / BM;
    int* tbl = ws + 4;
    for (int t = 0; t < nt; ++t) {
        int idx = tbase + t;
        tbl[4 * idx + 0] = e;
        tbl[4 * idx + 1] = off + t * BM;
        tbl[4 * idx + 2] = off + c;
        tbl[4 * idx + 3] = 0;
    }
    if (e == NE - 1) ws[0] = tbase + nt;
}

__device__ __forceinline__ void gload16(const float* g, uint8_t* l) {
    __builtin_amdgcn_global_load_lds(
        (const __attribute__((address_space(1))) uint32_t*)g,
        (__attribute__((address_space(3))) uint32_t*)l, 16, 0, 0);
}

__global__ __launch_bounds__(512, 2) void moe_gemm(
    const float* __restrict__ inp,
    const float* __restrict__ weight,
    const float* __restrict__ bias,
    const int* __restrict__ ws,
    float* __restrict__ out)
{
    __shared__ __align__(16) uint8_t smem[LDS_BYTES];

    // XCD-aware mapping: contiguous tile chunk per XCD, 4 n-blocks of one
    // tile adjacent on the same XCD (A-tile + expert weight stay in that L2).
    const int bid  = blockIdx.x;
    const int xcd  = bid & (NXCD - 1);
    const int slot = bid >> 3;                  // 0..287
    const int tile = xcd * TPX + (slot >> 2);
    const int n0   = (slot & 3) * BN;

    const int ntiles = ws[0];
    if (tile >= ntiles) return;
    const int4 ti = ((const int4*)(ws + 4))[tile];
    const int e = ti.x, row0 = ti.y, row_end = ti.z;

    const int tid  = threadIdx.x;
    const int lane = tid & 63;
    const int wave = tid >> 6;

    // ---- A staging via global_load_lds (fp32, source-preswizzled) ----
    // One gload16 per wave writes 1KB = 8 rows x 128B linearly.
    // lane -> (dr = lane>>3: row-in-group, ac = lane&7: dest 16B chunk).
    // LDS chunk c of row R must hold global chunk c ^ (R&7); since each
    // group base is 0 mod 8, R&7 == dr -> source chunk = ac ^ dr.
    const int dr = lane >> 3;
    const int ac = lane & 7;
    const float* asrc[4];
#pragma unroll
    for (int i = 0; i < 4; ++i) {
        int arow = wave * 32 + i * 8 + dr;
        int grow = row0 + arow;
        if (grow > row_end - 1) grow = row_end - 1;   // clamp OOB rows (stores are guarded)
        asrc[i] = inp + (size_t)grow * DIN + ((ac ^ dr) << 2);
    }

    // ---- B staging (reg fp32 -> bf16, XOR-swizzled ds_write) ----
    // thread -> row = tid>>2 (0..127), fp32 16B-chunks bc2, bc2+1 of 8.
    const int brow = tid >> 2;
    const int bc2  = (tid & 3) * 2;
    const float* bsrc = weight + (size_t)e * (DOUT * DIN)
                        + (size_t)(n0 + brow) * DIN + bc2 * 4;
    const int bwoff0 = brow * 64 + ((bc2 * 8)     ^ ((brow & 3) << 4));
    const int bwoff1 = brow * 64 + ((bc2 * 8 + 8) ^ ((brow & 3) << 4));

    f32x4_t rb[2];
    auto issueB = [&](int kk) {
        rb[0] = *(const f32x4_t*)(bsrc + kk * BK);
        rb[1] = *(const f32x4_t*)(bsrc + kk * BK + 4);
    };
    auto issueA = [&](int kk, int buf) {
        uint8_t* dst = smem + ABUF(buf) + wave * 4096;
#pragma unroll
        for (int i = 0; i < 4; ++i)
            gload16(asrc[i] + kk * BK, dst + i * 1024);
    };
    auto writeB = [&](int buf) {
        bf16x4_t h0, h1;
#pragma unroll
        for (int j = 0; j < 4; ++j) {
            h0[j] = (__bf16)rb[0][j];
            h1[j] = (__bf16)rb[1][j];
        }
        *(bf16x4_t*)(smem + BBUF(buf) + bwoff0) = h0;
        *(bf16x4_t*)(smem + BBUF(buf) + bwoff1) = h1;
    };

    // ---- compute: fragments from LDS (A: fp32 swizzled + cvt; B: bf16) ----
    const int wr = (wave >> 1) * 64;   // wave row offset (4 M-bands)
    const int wc = (wave & 1) * 64;    // wave col offset (2 N-bands)
    const int frow = lane & 15;
    const int kg   = lane >> 4;        // 0..3 : k-group of 8 elements

    f32x4_t acc[4][4] = {};

    auto compute = [&](int abuf, int bbuf) {
        bf16x8_t af[4], bg[4];
#pragma unroll
        for (int m = 0; m < 4; ++m) {
            const int row = wr + m * 16 + frow;
            const uint8_t* p = smem + ABUF(abuf) + row * 128;
            const int sw = (row & 7) << 4;
            f32x4_t q0 = *(const f32x4_t*)(p + ((kg * 32)      ^ sw));
            f32x4_t q1 = *(const f32x4_t*)(p + ((kg * 32 + 16) ^ sw));
#pragma unroll
            for (int j = 0; j < 4; ++j) {
                af[m][j]     = (__bf16)q0[j];
                af[m][4 + j] = (__bf16)q1[j];
            }
        }
#pragma unroll
        for (int n = 0; n < 4; ++n) {
            const int row = wc + n * 16 + frow;
            bg[n] = *(const bf16x8_t*)(smem + BBUF(bbuf) + row * 64
                                       + ((kg * 16) ^ ((row & 3) << 4)));
        }
        __builtin_amdgcn_s_setprio(1);
#pragma unroll
        for (int m = 0; m < 4; ++m)
#pragma unroll
            for (int n = 0; n < 4; ++n)
                acc[m][n] = __builtin_amdgcn_mfma_f32_16x16x32_bf16(
                    af[m], bg[n], acc[m][n], 0, 0, 0);
        __builtin_amdgcn_s_setprio(0);
    };

    // ---- prologue ----
    // Issue order matters: B first, then A(0), A(1). The compiler's precise
    // wait for rb's use is then vmcnt(8) (keeps A(0),A(1) in flight); the
    // manual vmcnt(4) certifies A(0) before the barrier, A(1) flies on.
    issueB(0);
    issueA(0, 0);
    issueA(1, 1);
    writeB(0);
    asm volatile("s_waitcnt vmcnt(4)" ::: "memory");
    __builtin_amdgcn_sched_barrier(0);
    asm volatile("s_waitcnt lgkmcnt(0)" ::: "memory");
    __builtin_amdgcn_s_barrier();

    // ---- main loop: 16 steps, fully unrolled ----
    // Steady state per step k: issue B(k+1) then A(k+2); compute(k); the
    // compiler's wait before writeB = vmcnt(4) -> drains A(k+1)+B(k+1),
    // keeps A(k+2) flying through the raw barrier (no vmcnt drain there).
#pragma unroll
    for (int k = 0; k < NK; ++k) {
        if (k + 1 < NK) issueB(k + 1);
        if (k + 2 < NK) issueA(k + 2, (k + 2) % 3);
        compute(k % 3, k & 1);
        if (k + 1 < NK) {
            writeB((k + 1) & 1);
            asm volatile("s_waitcnt lgkmcnt(0)" ::: "memory");
            __builtin_amdgcn_sched_barrier(0);
            __builtin_amdgcn_s_barrier();
        }
    }

    // ---- epilogue: C/D layout col = lane&15, row = (lane>>4)*4 + j [m89] ----
    const int crow = kg * 4;
    const int ccol = frow;
    float bv[4];
#pragma unroll
    for (int n = 0; n < 4; ++n)
        bv[n] = bias[e * DOUT + n0 + wc + n * 16 + ccol];
#pragma unroll
    for (int m = 0; m < 4; ++m) {
#pragma unroll
        for (int j = 0; j < 4; ++j) {
            const int grow = row0 + wr + m * 16 + crow + j;
            if (grow < row_end) {
                float* orow = out + (size_t)grow * DOUT + n0 + wc + ccol;
#pragma unroll
                for (int n = 0; n < 4; ++n)
                    orow[n * 16] = acc[m][n][j] + bv[n];
            }
        }
    }
}

extern "C" void kernel_launch(void* const* d_in, const int* in_sizes, int n_in,
                              void* d_out, int out_size, void* d_ws, size_t ws_size,
                              hipStream_t stream) {
    const float* inp    = (const float*)d_in[0];
    const float* weight = (const float*)d_in[1];
    const float* bias   = (const float*)d_in[2];
    const int* cnt      = (const int*)d_in[3];   // int64 in reference, delivered as int32
    float* out = (float*)d_out;
    int* ws = (int*)d_ws;

    hipLaunchKernelGGL(setup_tiles, dim3(1), dim3(64), 0, stream, cnt, ws);
    hipLaunchKernelGGL(moe_gemm, dim3(TILES_TOTAL * 4), dim3(512), 0, stream,
                       inp, weight, bias, ws, out);
}